// Round 8
// baseline (278.892 us; speedup 1.0000x reference)
//
#include <hip/hip_runtime.h>
#include <hip/hip_bf16.h>
#include <stdint.h>

typedef unsigned short u16;
typedef __attribute__((ext_vector_type(8)))  _Float16 f16x8;
typedef __attribute__((ext_vector_type(16))) float    f32x16;

#define B_DIM 16
#define N_SEQ 2048
#define M_TOT (B_DIM * N_SEQ)   // 32768
#define LOG2E 1.44269504088896f
#define SHIFT 64.0f             // fixed softmax shift (log2 units)

#if __has_builtin(__builtin_amdgcn_exp2f)
#define EXP2(x) __builtin_amdgcn_exp2f(x)
#else
#define EXP2(x) exp2f(x)
#endif

static __device__ __forceinline__ f32x16 MFMA16(f16x8 a, f16x8 b, f32x16 c) {
  return __builtin_amdgcn_mfma_f32_32x32x16_f16(a, b, c, 0, 0, 0);
}

// Stage a 64-row x 512-B fp16 tile into LDS with involution swizzle
// (LDS(row, s) holds global (row, s ^ (row&7))). gload_lds dest is linear;
// the SOURCE address carries the swizzle (rule #21). 256 threads, 8 instr/lane.
static __device__ __forceinline__ void stage64(
    const u16* __restrict__ src, char* ldsbuf, int row0, int t)
{
#pragma unroll
  for (int jj = 0; jj < 8; ++jj) {
    const int sl = (t & 31) ^ (t >> 5);          // swizzled 16B-slot; row&7 == t>>5
    const char* g = (const char*)src +
        ((size_t)(row0 + (t >> 5) + jj * 8) * 512 + (size_t)sl * 16);
    __builtin_amdgcn_global_load_lds(
        (const __attribute__((address_space(1))) uint32_t*)g,
        (__attribute__((address_space(3))) uint32_t*)(ldsbuf + t * 16 + jj * 4096),
        16, 0, 0);
  }
}

// XCD swizzle decode for 512-block grids: 64 sibling-groups x 8 members.
#define SWZ8(bid, G_, J_)                                      \
  const int xcd_ = (bid) & 7, r_ = (bid) >> 3;                 \
  const int J_ = r_ & 7;                                       \
  const int G_ = ((r_ >> 3) << 3) | xcd_;

// ---------------------------------------------------------------------------
// W fold+transpose: WTf[a][k] fp16 (a<256: W1*log2e, else W2).
// ---------------------------------------------------------------------------
__global__ void splitW_kernel(const float* __restrict__ W1, const float* __restrict__ W2,
                              u16* __restrict__ WTf) {
  const int gid = blockIdx.x * 256 + threadIdx.x;   // 512 blocks
  const int a = gid >> 8, k = gid & 255;
  const float v = (a < 256) ? W1[k * 256 + a] * LOG2E : W2[k * 256 + (a - 256)];
  WTf[gid] = __builtin_bit_cast(u16, (_Float16)v);
}

// ---------------------------------------------------------------------------
// Projection: Qf = (x@W1+b1)*log2e (ablk 0), Kf = x@W2+b2 (ablk 1).
// 512 threads / 8 waves cover all 256 a-cols -> x re-read only 2x.
// ---------------------------------------------------------------------------
__global__ __launch_bounds__(512, 2) void proj_kernel(
    const float* __restrict__ x, const u16* __restrict__ WTf,
    const float* __restrict__ b1, const float* __restrict__ b2,
    u16* __restrict__ Qf, u16* __restrict__ Kf)
{
  __shared__ char lds[32768];   // 2 x 16 KB fp16 x-tiles
  const int t = threadIdx.x, wv = t >> 6, ln = t & 63, lr = ln & 31, g = ln >> 5;
  const int ablk = blockIdx.x & 1;
  const int m0 = (blockIdx.x >> 1) * 256;
  const int aglob = wv * 32 + lr;               // 0..255

  f16x8 wf[16];
  {
    const u16* base = WTf + ((size_t)ablk * 256 + aglob) * 256 + g * 8;
#pragma unroll
    for (int c = 0; c < 16; ++c) wf[c] = *(const f16x8*)(base + c * 16);
  }
  const float bias = (ablk == 0) ? b1[aglob] * LOG2E : b2[aglob];
  u16* Of = (ablk == 0) ? Qf : Kf;

  const int srow = t >> 4;            // staging row 0..31
  const int scol = (t & 15) * 16;     // 16 f32 per thread

  float4 v[4];
  { // prologue: rows m0 -> fp16 -> swizzled buf0
    const float* src = x + (size_t)(m0 + srow) * 256 + scol;
#pragma unroll
    for (int j = 0; j < 4; ++j) v[j] = *(const float4*)(src + j * 4);
#pragma unroll
    for (int q8 = 0; q8 < 2; ++q8) {
      float ff[8] = {v[q8*2].x, v[q8*2].y, v[q8*2].z, v[q8*2].w,
                     v[q8*2+1].x, v[q8*2+1].y, v[q8*2+1].z, v[q8*2+1].w};
      f16x8 H;
#pragma unroll
      for (int e = 0; e < 8; ++e) H[e] = (_Float16)ff[e];
      const int swz = (((t & 15) * 2 + q8) ^ (srow & 7));
      *(f16x8*)(lds + srow * 512 + swz * 16) = H;
    }
  }
  __syncthreads();
  int p = 0;
  for (int it = 0; it < 8; ++it) {
    if (it + 1 < 8) {
      const float* src = x + (size_t)(m0 + (it + 1) * 32 + srow) * 256 + scol;
#pragma unroll
      for (int j = 0; j < 4; ++j) v[j] = *(const float4*)(src + j * 4);
    }
    const char* bh = lds + p * 16384;
    f32x16 S = {};
#pragma unroll
    for (int cc = 0; cc < 16; ++cc) {
      const int sl = ((cc * 2 + g) ^ (lr & 7)) * 16;
      const f16x8 a = *(const f16x8*)(bh + lr * 512 + sl);
      S = MFMA16(a, wf[cc], S);
    }
#pragma unroll
    for (int i = 0; i < 16; ++i) {
      const int mrow = m0 + it * 32 + (i & 3) + 8 * (i >> 2) + 4 * g;
      const float val = S[i] + bias;
      Of[(size_t)mrow * 256 + aglob] = __builtin_bit_cast(u16, (_Float16)val);
    }
    if (it + 1 < 8) {
      char* bp = lds + (p ^ 1) * 16384;
#pragma unroll
      for (int q8 = 0; q8 < 2; ++q8) {
        float ff[8] = {v[q8*2].x, v[q8*2].y, v[q8*2].z, v[q8*2].w,
                       v[q8*2+1].x, v[q8*2+1].y, v[q8*2+1].z, v[q8*2+1].w};
        f16x8 H;
#pragma unroll
        for (int e = 0; e < 8; ++e) H[e] = (_Float16)ff[e];
        const int swz = (((t & 15) * 2 + q8) ^ (srow & 7));
        *(f16x8*)(bp + srow * 512 + swz * 16) = H;
      }
    }
    __syncthreads();
    p ^= 1;
  }
}

// ---------------------------------------------------------------------------
// Pass 1: l_q += sum_k exp2(S' - 64) over one key-quarter (512 keys, 8 tiles
// of 64). Proven 2-phase skeleton: stage next tile, compute current (two
// 32-key halves), one __syncthreads (full drain) per tile.
// ---------------------------------------------------------------------------
__global__ __launch_bounds__(256, 2) void pass1_kernel(
    const u16* __restrict__ Qf, const u16* __restrict__ Kf,
    float* __restrict__ lsum)
{
  extern __shared__ char lds[];   // 2 x 32 KB
  SWZ8(blockIdx.x, grp, qg);
  const int b = grp >> 2, kq = grp & 3;
  const int t = threadIdx.x, wv = t >> 6, ln = t & 63, lr = ln & 31, gg = ln >> 5;

  const int q0 = b * 2048 + qg * 256 + wv * 64;
  f16x8 qf0[16], qf1[16];
  {
    const u16* qb0 = Qf + (size_t)(q0 + lr) * 256 + gg * 8;
    const u16* qb1 = qb0 + 32 * 256;
#pragma unroll
    for (int c = 0; c < 16; ++c) {
      qf0[c] = *(const f16x8*)(qb0 + c * 16);
      qf1[c] = *(const f16x8*)(qb1 + c * 16);
    }
  }
  const int k0 = b * 2048 + kq * 512;

  stage64(Kf, lds, k0, t);
  __syncthreads();

  float l0 = 0.f, l1 = 0.f;
  int p = 0;
  for (int it = 0; it < 8; ++it) {
    if (it + 1 < 8) stage64(Kf, lds + (p ^ 1) * 32768, k0 + (it + 1) * 64, t);
    const char* bh = lds + p * 32768;
#pragma unroll
    for (int h = 0; h < 2; ++h) {
      f32x16 S0, S1;
#pragma unroll
      for (int i = 0; i < 16; ++i) { S0[i] = -SHIFT; S1[i] = -SHIFT; }
      __builtin_amdgcn_s_setprio(1);
#pragma unroll
      for (int c = 0; c < 16; ++c) {
        const int sl = ((c * 2 + gg) ^ (lr & 7)) * 16;
        const f16x8 a = *(const f16x8*)(bh + (h * 32 + lr) * 512 + sl);
        S0 = MFMA16(a, qf0[c], S0);
        S1 = MFMA16(a, qf1[c], S1);
      }
      __builtin_amdgcn_s_setprio(0);
      float r0 = 0.f, r1 = 0.f;
#pragma unroll
      for (int i = 0; i < 16; ++i) { r0 += EXP2(S0[i]); r1 += EXP2(S1[i]); }
      l0 += r0; l1 += r1;
    }
    __syncthreads();
    p ^= 1;
  }
  l0 += __shfl_xor(l0, 32);
  l1 += __shfl_xor(l1, 32);
  if (ln < 32) {
    atomicAdd(&lsum[q0 + ln],      l0);
    atomicAdd(&lsum[q0 + 32 + ln], l1);
  }
}

// ---------------------------------------------------------------------------
// Pass 2: c_k += sum_q exp2(S' - 64) / l_q over one query-quarter.
// K (64 keys/wave) in regs; Q streamed 64 rows/tile; 1/l table in LDS.
// Same operand values + MFMA order as pass1 -> bitwise-identical S'.
// ---------------------------------------------------------------------------
__global__ __launch_bounds__(256, 2) void pass2_kernel(
    const u16* __restrict__ Qf, const u16* __restrict__ Kf,
    const float* __restrict__ lsum, float* __restrict__ cvec)
{
  extern __shared__ char lds[];   // 2 x 32 KB + 2 KB ilds
  float* ilds = (float*)(lds + 65536);
  SWZ8(blockIdx.x, grp, kg);
  const int b = grp >> 2, qq = grp & 3;
  const int t = threadIdx.x, wv = t >> 6, ln = t & 63, lr = ln & 31, gg = ln >> 5;

  const int k0 = b * 2048 + kg * 256 + wv * 64;
  const int q0 = b * 2048 + qq * 512;

  { // inverse-l table for this block's 512 queries
    const float la = lsum[q0 + t];
    const float lb = lsum[q0 + 256 + t];
    ilds[t]       = 1.0f / fmaxf(la, 1e-30f);
    ilds[t + 256] = 1.0f / fmaxf(lb, 1e-30f);
  }

  f16x8 kf0[16], kf1[16];
  {
    const u16* kb0 = Kf + (size_t)(k0 + lr) * 256 + gg * 8;
    const u16* kb1 = kb0 + 32 * 256;
#pragma unroll
    for (int c = 0; c < 16; ++c) {
      kf0[c] = *(const f16x8*)(kb0 + c * 16);
      kf1[c] = *(const f16x8*)(kb1 + c * 16);
    }
  }

  float ck0[16], ck1[16];
#pragma unroll
  for (int i = 0; i < 16; ++i) { ck0[i] = 0.f; ck1[i] = 0.f; }

  stage64(Qf, lds, q0, t);
  __syncthreads();   // covers ilds writes + buf0 staging

  int p = 0;
  for (int it = 0; it < 8; ++it) {
    if (it + 1 < 8) stage64(Qf, lds + (p ^ 1) * 32768, q0 + (it + 1) * 64, t);
    const char* bh = lds + p * 32768;
#pragma unroll
    for (int h = 0; h < 2; ++h) {
      const float il = ilds[it * 64 + h * 32 + lr];
      f32x16 S0, S1;
#pragma unroll
      for (int i = 0; i < 16; ++i) { S0[i] = -SHIFT; S1[i] = -SHIFT; }
      __builtin_amdgcn_s_setprio(1);
#pragma unroll
      for (int c = 0; c < 16; ++c) {
        const int sl = ((c * 2 + gg) ^ (lr & 7)) * 16;
        const f16x8 qa = *(const f16x8*)(bh + (h * 32 + lr) * 512 + sl);
        S0 = MFMA16(kf0[c], qa, S0);
        S1 = MFMA16(kf1[c], qa, S1);
      }
      __builtin_amdgcn_s_setprio(0);
#pragma unroll
      for (int i = 0; i < 16; ++i) {
        ck0[i] += EXP2(S0[i]) * il;
        ck1[i] += EXP2(S1[i]) * il;
      }
    }
    __syncthreads();
    p ^= 1;
  }
  // reduce over the 32 streamed q-columns (lanes within each gg half)
#pragma unroll
  for (int i = 0; i < 16; ++i) {
#pragma unroll
    for (int d = 1; d <= 16; d <<= 1) {
      ck0[i] += __shfl_xor(ck0[i], d);
      ck1[i] += __shfl_xor(ck1[i], d);
    }
  }
  if (lr == 0) {
#pragma unroll
    for (int i = 0; i < 16; ++i) {
      const int klocal = (i & 3) + 8 * (i >> 2) + 4 * gg;
      atomicAdd(&cvec[k0 + klocal],      ck0[i]);
      atomicAdd(&cvec[k0 + 32 + klocal], ck1[i]);
    }
  }
}

// y[b][d] = sum_k c_k x[b,k,d]; sumc[b] = sum_k c_k
__global__ void reducey_kernel(const float* __restrict__ x, const float* __restrict__ cvec,
                               float* __restrict__ yv, float* __restrict__ sumc) {
  const int b = blockIdx.x >> 4, kc = blockIdx.x & 15, tid = threadIdx.x;
  const float* xb = x + ((size_t)b * 2048 + kc * 128) * 256;
  const float* cb = cvec + b * 2048 + kc * 128;
  float a0 = 0.f, a1 = 0.f, a2 = 0.f, a3 = 0.f;
  for (int k = 0; k < 128; k += 4) {
    a0 = fmaf(cb[k],     xb[(size_t)k * 256 + tid],       a0);
    a1 = fmaf(cb[k + 1], xb[(size_t)(k + 1) * 256 + tid], a1);
    a2 = fmaf(cb[k + 2], xb[(size_t)(k + 2) * 256 + tid], a2);
    a3 = fmaf(cb[k + 3], xb[(size_t)(k + 3) * 256 + tid], a3);
  }
  atomicAdd(&yv[b * 256 + tid], (a0 + a1) + (a2 + a3));
  if (tid == 0) {
    float s = 0.f;
    for (int k = 0; k < 128; ++k) s += cb[k];
    atomicAdd(&sumc[b], s);
  }
}

// out[b][a] = sum_d y[b,d] W3[d,a] + sumc[b]*b3[a]
__global__ void final_kernel(const float* __restrict__ yv, const float* __restrict__ sumc,
                             const float* __restrict__ W3, const float* __restrict__ b3,
                             float* __restrict__ out) {
  __shared__ float ys[256];
  const int b = blockIdx.x, a = threadIdx.x;
  ys[a] = yv[b * 256 + a];
  __syncthreads();
  float acc = sumc[b] * b3[a];
#pragma unroll 4
  for (int d = 0; d < 256; ++d) acc = fmaf(ys[d], W3[d * 256 + a], acc);
  out[b * 256 + a] = acc;
}

// ---------------------------------------------------------------------------
extern "C" void kernel_launch(void* const* d_in, const int* in_sizes, int n_in,
                              void* d_out, int out_size, void* d_ws, size_t ws_size,
                              hipStream_t stream) {
  const float* x  = (const float*)d_in[0];
  const float* W1 = (const float*)d_in[1];
  const float* b1 = (const float*)d_in[2];
  const float* W2 = (const float*)d_in[3];
  const float* b2 = (const float*)d_in[4];
  const float* W3 = (const float*)d_in[5];
  const float* b3 = (const float*)d_in[6];
  float* out = (float*)d_out;

  char* ws = (char*)d_ws;
  const size_t SZ_WT = 512u * 256u * 2u;          // 262144 B
  const size_t SZ_QK = (size_t)M_TOT * 256u * 2u; // 16 MB
  u16* WTf = (u16*)(ws);                 ws += SZ_WT;
  u16* Qf  = (u16*)(ws);                 ws += SZ_QK;
  u16* Kf  = (u16*)(ws);                 ws += SZ_QK;
  float* lsum = (float*)(ws);            ws += (size_t)M_TOT * 4u;
  float* cvec = (float*)(ws);            ws += (size_t)M_TOT * 4u;
  float* yv   = (float*)(ws);            ws += 4096u * 4u;
  float* sumc = (float*)(ws);            ws += 64u;

  // zero the accumulated buffers (lsum | cvec | yv | sumc contiguous)
  hipMemsetAsync(lsum, 0, (size_t)M_TOT * 8u + 4096u * 4u + 64u, stream);

  hipFuncSetAttribute((const void*)pass1_kernel,
                      hipFuncAttributeMaxDynamicSharedMemorySize, 65536);
  hipFuncSetAttribute((const void*)pass2_kernel,
                      hipFuncAttributeMaxDynamicSharedMemorySize, 67584);

  splitW_kernel<<<dim3(512), dim3(256), 0, stream>>>(W1, W2, WTf);
  proj_kernel<<<dim3(256), dim3(512), 0, stream>>>(x, WTf, b1, b2, Qf, Kf);
  pass1_kernel<<<dim3(512), dim3(256), 65536, stream>>>(Qf, Kf, lsum);
  pass2_kernel<<<dim3(512), dim3(256), 67584, stream>>>(Qf, Kf, lsum, cvec);
  reducey_kernel<<<dim3(256), dim3(256), 0, stream>>>(x, cvec, yv, sumc);
  final_kernel<<<dim3(16), dim3(256), 0, stream>>>(yv, sumc, W3, b3, out);
}

// Round 9
// 204.568 us; speedup vs baseline: 1.3633x; 1.3633x over previous
//
#include <hip/hip_runtime.h>
#include <hip/hip_bf16.h>
#include <stdint.h>

typedef unsigned short u16;
typedef __attribute__((ext_vector_type(8)))  _Float16 f16x8;
typedef __attribute__((ext_vector_type(16))) float    f32x16;

#define B_DIM 16
#define N_SEQ 2048
#define M_TOT (B_DIM * N_SEQ)   // 32768
#define LOG2E 1.44269504088896f
#define SHIFT 64.0f             // fixed softmax shift (log2 units)

#if __has_builtin(__builtin_amdgcn_exp2f)
#define EXP2(x) __builtin_amdgcn_exp2f(x)
#else
#define EXP2(x) exp2f(x)
#endif

static __device__ __forceinline__ f32x16 MFMA16(f16x8 a, f16x8 b, f32x16 c) {
  return __builtin_amdgcn_mfma_f32_32x32x16_f16(a, b, c, 0, 0, 0);
}

// Stage a 32-row x 512-B fp16 tile into LDS with involution swizzle
// (LDS(row, s) holds global (row, s ^ (row&7))). gload_lds dest is linear
// (uniform base + lane*16); the SOURCE address carries the swizzle. 256 thr,
// 4 instr/lane. (Round-6 proven structure — do not restructure.)
static __device__ __forceinline__ void stage_f16(
    const u16* __restrict__ src, char* ldsbuf, int row0, int t)
{
#pragma unroll
  for (int jj = 0; jj < 4; ++jj) {
    const int row = (t >> 5) + jj * 8;           // 0..31 ; row&7 == t>>5
    const int sl  = (t & 31) ^ (t >> 5);         // swizzled 16B-slot
    const char* g = (const char*)src + ((size_t)(row0 + row) * 512 + (size_t)sl * 16);
    __builtin_amdgcn_global_load_lds(
        (const __attribute__((address_space(1))) uint32_t*)g,
        (__attribute__((address_space(3))) uint32_t*)(ldsbuf + t * 16 + jj * 4096),
        16, 0, 0);
  }
}

// XCD swizzle decode for 512-block grids: 64 sibling-groups x 8 members.
#define SWZ8(bid, G_, J_)                                      \
  const int xcd_ = (bid) & 7, r_ = (bid) >> 3;                 \
  const int J_ = r_ & 7;                                       \
  const int G_ = ((r_ >> 3) << 3) | xcd_;

// ---------------------------------------------------------------------------
// W fold+transpose: WTf[a][k] fp16 (a<256: W1*log2e, else W2).
// ---------------------------------------------------------------------------
__global__ void splitW_kernel(const float* __restrict__ W1, const float* __restrict__ W2,
                              u16* __restrict__ WTf) {
  const int gid = blockIdx.x * 256 + threadIdx.x;   // 512 blocks
  const int a = gid >> 8, k = gid & 255;
  const float v = (a < 256) ? W1[k * 256 + a] * LOG2E : W2[k * 256 + (a - 256)];
  WTf[gid] = __builtin_bit_cast(u16, (_Float16)v);
}

// ---------------------------------------------------------------------------
// Projection: Qf = (x@W1+b1)*log2e (ablk 0), Kf = x@W2+b2 (ablk 1).
// 512 threads / 8 waves cover all 256 a-cols -> x re-read only 2x.
// (Passed in round 8.)
// ---------------------------------------------------------------------------
__global__ __launch_bounds__(512, 2) void proj_kernel(
    const float* __restrict__ x, const u16* __restrict__ WTf,
    const float* __restrict__ b1, const float* __restrict__ b2,
    u16* __restrict__ Qf, u16* __restrict__ Kf)
{
  __shared__ char lds[32768];   // 2 x 16 KB fp16 x-tiles
  const int t = threadIdx.x, wv = t >> 6, ln = t & 63, lr = ln & 31, g = ln >> 5;
  const int ablk = blockIdx.x & 1;
  const int m0 = (blockIdx.x >> 1) * 256;
  const int aglob = wv * 32 + lr;               // 0..255

  f16x8 wf[16];
  {
    const u16* base = WTf + ((size_t)ablk * 256 + aglob) * 256 + g * 8;
#pragma unroll
    for (int c = 0; c < 16; ++c) wf[c] = *(const f16x8*)(base + c * 16);
  }
  const float bias = (ablk == 0) ? b1[aglob] * LOG2E : b2[aglob];
  u16* Of = (ablk == 0) ? Qf : Kf;

  const int srow = t >> 4;            // staging row 0..31
  const int scol = (t & 15) * 16;     // 16 f32 per thread

  float4 v[4];
  { // prologue: rows m0 -> fp16 -> swizzled buf0
    const float* src = x + (size_t)(m0 + srow) * 256 + scol;
#pragma unroll
    for (int j = 0; j < 4; ++j) v[j] = *(const float4*)(src + j * 4);
#pragma unroll
    for (int q8 = 0; q8 < 2; ++q8) {
      float ff[8] = {v[q8*2].x, v[q8*2].y, v[q8*2].z, v[q8*2].w,
                     v[q8*2+1].x, v[q8*2+1].y, v[q8*2+1].z, v[q8*2+1].w};
      f16x8 H;
#pragma unroll
      for (int e = 0; e < 8; ++e) H[e] = (_Float16)ff[e];
      const int swz = (((t & 15) * 2 + q8) ^ (srow & 7));
      *(f16x8*)(lds + srow * 512 + swz * 16) = H;
    }
  }
  __syncthreads();
  int p = 0;
  for (int it = 0; it < 8; ++it) {
    if (it + 1 < 8) {
      const float* src = x + (size_t)(m0 + (it + 1) * 32 + srow) * 256 + scol;
#pragma unroll
      for (int j = 0; j < 4; ++j) v[j] = *(const float4*)(src + j * 4);
    }
    const char* bh = lds + p * 16384;
    f32x16 S = {};
#pragma unroll
    for (int cc = 0; cc < 16; ++cc) {
      const int sl = ((cc * 2 + g) ^ (lr & 7)) * 16;
      const f16x8 a = *(const f16x8*)(bh + lr * 512 + sl);
      S = MFMA16(a, wf[cc], S);
    }
#pragma unroll
    for (int i = 0; i < 16; ++i) {
      const int mrow = m0 + it * 32 + (i & 3) + 8 * (i >> 2) + 4 * g;
      const float val = S[i] + bias;
      Of[(size_t)mrow * 256 + aglob] = __builtin_bit_cast(u16, (_Float16)val);
    }
    if (it + 1 < 8) {
      char* bp = lds + (p ^ 1) * 16384;
#pragma unroll
      for (int q8 = 0; q8 < 2; ++q8) {
        float ff[8] = {v[q8*2].x, v[q8*2].y, v[q8*2].z, v[q8*2].w,
                       v[q8*2+1].x, v[q8*2+1].y, v[q8*2+1].z, v[q8*2+1].w};
        f16x8 H;
#pragma unroll
        for (int e = 0; e < 8; ++e) H[e] = (_Float16)ff[e];
        const int swz = (((t & 15) * 2 + q8) ^ (srow & 7));
        *(f16x8*)(bp + srow * 512 + swz * 16) = H;
      }
    }
    __syncthreads();
    p ^= 1;
  }
}

// ---------------------------------------------------------------------------
// Pass 1: l_q += sum_k exp2(S' - 64) over one key-quarter (512 keys, 16 tiles
// of 32). Round-6 proven 2-phase skeleton, EXP2 builtin swapped in.
// ---------------------------------------------------------------------------
__global__ __launch_bounds__(256, 2) void pass1_kernel(
    const u16* __restrict__ Qf, const u16* __restrict__ Kf,
    float* __restrict__ lsum)
{
  __shared__ char lds[32768];
  SWZ8(blockIdx.x, grp, qg);
  const int b = grp >> 2, kq = grp & 3;
  const int t = threadIdx.x, wv = t >> 6, ln = t & 63, lr = ln & 31, gg = ln >> 5;

  const int q0 = b * 2048 + qg * 256 + wv * 64;
  f16x8 qf0[16], qf1[16];
  {
    const u16* qb0 = Qf + (size_t)(q0 + lr) * 256 + gg * 8;
    const u16* qb1 = qb0 + 32 * 256;
#pragma unroll
    for (int c = 0; c < 16; ++c) {
      qf0[c] = *(const f16x8*)(qb0 + c * 16);
      qf1[c] = *(const f16x8*)(qb1 + c * 16);
    }
  }
  const int k0 = b * 2048 + kq * 512;

  stage_f16(Kf, lds, k0, t);
  __syncthreads();
  float l0 = 0.f, l1 = 0.f;
  int pp = 0;
  for (int it = 0; it < 16; ++it) {
    if (it + 1 < 16) stage_f16(Kf, lds + (pp ^ 1) * 16384, k0 + (it + 1) * 32, t);
    const char* bh = lds + pp * 16384;
    f32x16 S0, S1;
#pragma unroll
    for (int i = 0; i < 16; ++i) { S0[i] = -SHIFT; S1[i] = -SHIFT; }
    __builtin_amdgcn_s_setprio(1);
#pragma unroll
    for (int c = 0; c < 16; ++c) {
      const int sl = ((c * 2 + gg) ^ (lr & 7)) * 16;
      const f16x8 a = *(const f16x8*)(bh + lr * 512 + sl);
      S0 = MFMA16(a, qf0[c], S0);
      S1 = MFMA16(a, qf1[c], S1);
    }
    __builtin_amdgcn_s_setprio(0);
    float r0 = 0.f, r1 = 0.f;
#pragma unroll
    for (int i = 0; i < 16; ++i) { r0 += EXP2(S0[i]); r1 += EXP2(S1[i]); }
    l0 += r0; l1 += r1;
    __syncthreads();
    pp ^= 1;
  }
  l0 += __shfl_xor(l0, 32);
  l1 += __shfl_xor(l1, 32);
  if (ln < 32) {
    atomicAdd(&lsum[q0 + ln],      l0);
    atomicAdd(&lsum[q0 + 32 + ln], l1);
  }
}

// ---------------------------------------------------------------------------
// Pass 2: c_k += sum_q exp2(S' - 64) / l_q over one query-quarter.
// Round-6 proven structure (per-iter global lsum read), EXP2 swapped in.
// Same operand values + MFMA order as pass1 -> bitwise-identical S'.
// ---------------------------------------------------------------------------
__global__ __launch_bounds__(256, 2) void pass2_kernel(
    const u16* __restrict__ Qf, const u16* __restrict__ Kf,
    const float* __restrict__ lsum, float* __restrict__ cvec)
{
  __shared__ char lds[32768];
  SWZ8(blockIdx.x, grp, kg);
  const int b = grp >> 2, qq = grp & 3;
  const int t = threadIdx.x, wv = t >> 6, ln = t & 63, lr = ln & 31, gg = ln >> 5;

  const int k0 = b * 2048 + kg * 256 + wv * 64;
  f16x8 kf0[16], kf1[16];
  {
    const u16* kb0 = Kf + (size_t)(k0 + lr) * 256 + gg * 8;
    const u16* kb1 = kb0 + 32 * 256;
#pragma unroll
    for (int c = 0; c < 16; ++c) {
      kf0[c] = *(const f16x8*)(kb0 + c * 16);
      kf1[c] = *(const f16x8*)(kb1 + c * 16);
    }
  }
  const int q0 = b * 2048 + qq * 512;

  float ck0[16], ck1[16];
#pragma unroll
  for (int i = 0; i < 16; ++i) { ck0[i] = 0.f; ck1[i] = 0.f; }

  stage_f16(Qf, lds, q0, t);
  __syncthreads();
  int pp = 0;
  for (int it = 0; it < 16; ++it) {
    if (it + 1 < 16) stage_f16(Qf, lds + (pp ^ 1) * 16384, q0 + (it + 1) * 32, t);
    const float il = 1.0f / fmaxf(lsum[q0 + it * 32 + lr], 1e-30f);
    const char* bh = lds + pp * 16384;
    f32x16 S0, S1;
#pragma unroll
    for (int i = 0; i < 16; ++i) { S0[i] = -SHIFT; S1[i] = -SHIFT; }
    __builtin_amdgcn_s_setprio(1);
#pragma unroll
    for (int c = 0; c < 16; ++c) {
      const int sl = ((c * 2 + gg) ^ (lr & 7)) * 16;
      const f16x8 qa = *(const f16x8*)(bh + lr * 512 + sl);
      S0 = MFMA16(kf0[c], qa, S0);
      S1 = MFMA16(kf1[c], qa, S1);
    }
    __builtin_amdgcn_s_setprio(0);
#pragma unroll
    for (int i = 0; i < 16; ++i) {
      ck0[i] += EXP2(S0[i]) * il;
      ck1[i] += EXP2(S1[i]) * il;
    }
    __syncthreads();
    pp ^= 1;
  }
  // reduce over the 32 streamed q-columns (lanes within each gg half)
#pragma unroll
  for (int i = 0; i < 16; ++i) {
#pragma unroll
    for (int d = 1; d <= 16; d <<= 1) {
      ck0[i] += __shfl_xor(ck0[i], d);
      ck1[i] += __shfl_xor(ck1[i], d);
    }
  }
  if (lr == 0) {
#pragma unroll
    for (int i = 0; i < 16; ++i) {
      const int klocal = (i & 3) + 8 * (i >> 2) + 4 * gg;
      atomicAdd(&cvec[k0 + klocal],      ck0[i]);
      atomicAdd(&cvec[k0 + 32 + klocal], ck1[i]);
    }
  }
}

// y[b][d] = sum_k c_k x[b,k,d]; sumc[b] = sum_k c_k
__global__ void reducey_kernel(const float* __restrict__ x, const float* __restrict__ cvec,
                               float* __restrict__ yv, float* __restrict__ sumc) {
  const int b = blockIdx.x >> 4, kc = blockIdx.x & 15, tid = threadIdx.x;
  const float* xb = x + ((size_t)b * 2048 + kc * 128) * 256;
  const float* cb = cvec + b * 2048 + kc * 128;
  float a0 = 0.f, a1 = 0.f, a2 = 0.f, a3 = 0.f;
  for (int k = 0; k < 128; k += 4) {
    a0 = fmaf(cb[k],     xb[(size_t)k * 256 + tid],       a0);
    a1 = fmaf(cb[k + 1], xb[(size_t)(k + 1) * 256 + tid], a1);
    a2 = fmaf(cb[k + 2], xb[(size_t)(k + 2) * 256 + tid], a2);
    a3 = fmaf(cb[k + 3], xb[(size_t)(k + 3) * 256 + tid], a3);
  }
  atomicAdd(&yv[b * 256 + tid], (a0 + a1) + (a2 + a3));
  if (tid == 0) {
    float s = 0.f;
    for (int k = 0; k < 128; ++k) s += cb[k];
    atomicAdd(&sumc[b], s);
  }
}

// out[b][a] = sum_d y[b,d] W3[d,a] + sumc[b]*b3[a]
__global__ void final_kernel(const float* __restrict__ yv, const float* __restrict__ sumc,
                             const float* __restrict__ W3, const float* __restrict__ b3,
                             float* __restrict__ out) {
  __shared__ float ys[256];
  const int b = blockIdx.x, a = threadIdx.x;
  ys[a] = yv[b * 256 + a];
  __syncthreads();
  float acc = sumc[b] * b3[a];
#pragma unroll 4
  for (int d = 0; d < 256; ++d) acc = fmaf(ys[d], W3[d * 256 + a], acc);
  out[b * 256 + a] = acc;
}

// ---------------------------------------------------------------------------
extern "C" void kernel_launch(void* const* d_in, const int* in_sizes, int n_in,
                              void* d_out, int out_size, void* d_ws, size_t ws_size,
                              hipStream_t stream) {
  const float* x  = (const float*)d_in[0];
  const float* W1 = (const float*)d_in[1];
  const float* b1 = (const float*)d_in[2];
  const float* W2 = (const float*)d_in[3];
  const float* b2 = (const float*)d_in[4];
  const float* W3 = (const float*)d_in[5];
  const float* b3 = (const float*)d_in[6];
  float* out = (float*)d_out;

  char* ws = (char*)d_ws;
  const size_t SZ_WT = 512u * 256u * 2u;          // 262144 B
  const size_t SZ_QK = (size_t)M_TOT * 256u * 2u; // 16 MB
  u16* WTf = (u16*)(ws);                 ws += SZ_WT;
  u16* Qf  = (u16*)(ws);                 ws += SZ_QK;
  u16* Kf  = (u16*)(ws);                 ws += SZ_QK;
  float* lsum = (float*)(ws);            ws += (size_t)M_TOT * 4u;
  float* cvec = (float*)(ws);            ws += (size_t)M_TOT * 4u;
  float* yv   = (float*)(ws);            ws += 4096u * 4u;
  float* sumc = (float*)(ws);            ws += 64u;

  // zero the accumulated buffers (lsum | cvec | yv | sumc contiguous)
  hipMemsetAsync(lsum, 0, (size_t)M_TOT * 8u + 4096u * 4u + 64u, stream);

  splitW_kernel<<<dim3(512), dim3(256), 0, stream>>>(W1, W2, WTf);
  proj_kernel<<<dim3(256), dim3(512), 0, stream>>>(x, WTf, b1, b2, Qf, Kf);
  pass1_kernel<<<dim3(512), dim3(256), 0, stream>>>(Qf, Kf, lsum);
  pass2_kernel<<<dim3(512), dim3(256), 0, stream>>>(Qf, Kf, lsum, cvec);
  reducey_kernel<<<dim3(256), dim3(256), 0, stream>>>(x, cvec, yv, sumc);
  final_kernel<<<dim3(16), dim3(256), 0, stream>>>(yv, sumc, W3, b3, out);
}